// Round 6
// baseline (100.238 us; speedup 1.0000x reference)
//
#include <hip/hip_runtime.h>

#define DD 160
#define HH 160
#define WW 160
#define VOL (DD * HH * WW)   // per-batch volume = 4,096,000
#define PLANE (HH * WW)      // 25,600
#define NB 2
#define HT 16                // output h-rows per wh block
#define HS (HT + 8)          // staged rows = 24
#define LDW 164              // LDS row stride (floats); 16B-aligned
#define DCH 20               // d-outputs per ncc_dred block
#define NDCH (DD / DCH)      // 8
#define CPT 25               // column-quad tiles: 6400 quads / 256
#define DREDBLK (CPT * NDCH) // 200 per batch
#define GCHD 20              // grad d-chunk
#define GBLK (NB * 3 * (DD / GCHD) * HH * (WW / 4) / 256)   // 1200

typedef _Float16 h8 __attribute__((ext_vector_type(8)));
typedef _Float16 h4 __attribute__((ext_vector_type(4)));

// ---------------------------------------------------------------------------
// Kernel 1 (v5): fused W+H box sums of 5 moment fields -> fp16 fields.
// Block: 512 thr, output 16h x 160w at one (d, b). Grid (10, 160, 2).
// W-stage (480 thr): thread (r,s)=(t/20,t%20): staged row r, 8 outputs at 8s;
//   aligned float4 global loads, register sliding window, b128 LDS writes.
// H-stage (400 thr): task (field, w-octet, row-quarter): b128 LDS reads,
//   9-row sliding window, 16B h8 global stores.
// ---------------------------------------------------------------------------
__global__ __launch_bounds__(512, 4) void ncc_wh(const float* __restrict__ mv,
                                                 const float* __restrict__ fx,
                                                 _Float16* __restrict__ out) {
    __shared__ float wsum[5][HS][LDW];

    const int d   = blockIdx.y;
    const int b   = blockIdx.z;
    const int h0  = blockIdx.x * HT;
    const int tid = threadIdx.x;

    if (tid < 480) {
        const int r  = tid / 20;        // 0..23 staged row
        const int s  = tid - r * 20;    // 0..19 w-segment
        const int h  = h0 - 4 + r;
        const int w0 = 8 * s;

        float vm[16], vf[16];
#pragma unroll
        for (int i = 0; i < 16; ++i) { vm[i] = 0.f; vf[i] = 0.f; }

        if ((unsigned)h < (unsigned)HH) {
            const float* rowm = mv + (size_t)b * VOL + ((size_t)d * HH + h) * WW;
            const float* rowf = fx + (size_t)b * VOL + ((size_t)d * HH + h) * WW;
#pragma unroll
            for (int j = 0; j < 4; ++j) {
                const int w4 = w0 - 4 + 4 * j;
                if (w4 >= 0 && w4 <= WW - 4) {
                    float4 m4 = *(const float4*)(rowm + w4);
                    float4 f4 = *(const float4*)(rowf + w4);
                    vm[4*j+0] = m4.x; vm[4*j+1] = m4.y; vm[4*j+2] = m4.z; vm[4*j+3] = m4.w;
                    vf[4*j+0] = f4.x; vf[4*j+1] = f4.y; vf[4*j+2] = f4.z; vf[4*j+3] = f4.w;
                } else {
#pragma unroll
                    for (int e = 0; e < 4; ++e) {
                        const int w = w4 + e;
                        if ((unsigned)w < (unsigned)WW) {
                            vm[4*j+e] = rowm[w];
                            vf[4*j+e] = rowf[w];
                        }
                    }
                }
            }
        }

        float o0[8], o1[8], o2[8], o3[8], o4[8];
        float sm = 0.f, sf = 0.f, smm = 0.f, sff = 0.f, smf = 0.f;
#pragma unroll
        for (int i = 0; i < 9; ++i) {
            float m = vm[i], f = vf[i];
            sm += m; sf += f;
            smm = fmaf(m, m, smm);
            sff = fmaf(f, f, sff);
            smf = fmaf(m, f, smf);
        }
        o0[0] = sm; o1[0] = sf; o2[0] = smm; o3[0] = sff; o4[0] = smf;
#pragma unroll
        for (int k = 1; k < 8; ++k) {
            float am = vm[k + 8], bm = vm[k - 1];
            float af = vf[k + 8], bf = vf[k - 1];
            sm  += am - bm;
            sf  += af - bf;
            smm += fmaf(am, am, -(bm * bm));
            sff += fmaf(af, af, -(bf * bf));
            smf += fmaf(am, af, -(bm * bf));
            o0[k] = sm; o1[k] = sf; o2[k] = smm; o3[k] = sff; o4[k] = smf;
        }
        *(float4*)&wsum[0][r][w0]     = *(float4*)&o0[0];
        *(float4*)&wsum[0][r][w0 + 4] = *(float4*)&o0[4];
        *(float4*)&wsum[1][r][w0]     = *(float4*)&o1[0];
        *(float4*)&wsum[1][r][w0 + 4] = *(float4*)&o1[4];
        *(float4*)&wsum[2][r][w0]     = *(float4*)&o2[0];
        *(float4*)&wsum[2][r][w0 + 4] = *(float4*)&o2[4];
        *(float4*)&wsum[3][r][w0]     = *(float4*)&o3[0];
        *(float4*)&wsum[3][r][w0 + 4] = *(float4*)&o3[4];
        *(float4*)&wsum[4][r][w0]     = *(float4*)&o4[0];
        *(float4*)&wsum[4][r][w0 + 4] = *(float4*)&o4[4];
    }
    __syncthreads();

    if (tid < 400) {
        const int f   = tid / 80;                 // field 0..4
        const int rem = tid - f * 80;
        const int q   = rem / 20;                 // row-quarter 0..3
        const int w   = 8 * (rem - q * 20);       // 0..152
        const int ro0 = 4 * q;

        float4 sa = make_float4(0.f, 0.f, 0.f, 0.f);
        float4 sb = make_float4(0.f, 0.f, 0.f, 0.f);
#pragma unroll
        for (int t = 0; t < 9; ++t) {
            float4 va = *(const float4*)&wsum[f][ro0 + t][w];
            float4 vb = *(const float4*)&wsum[f][ro0 + t][w + 4];
            sa.x += va.x; sa.y += va.y; sa.z += va.z; sa.w += va.w;
            sb.x += vb.x; sb.y += vb.y; sb.z += vb.z; sb.w += vb.w;
        }
        _Float16* ob = out + (size_t)(b * 5 + f) * VOL
                           + ((size_t)d * HH + h0 + ro0) * WW + w;
        h8 o;
        o[0] = (_Float16)sa.x; o[1] = (_Float16)sa.y;
        o[2] = (_Float16)sa.z; o[3] = (_Float16)sa.w;
        o[4] = (_Float16)sb.x; o[5] = (_Float16)sb.y;
        o[6] = (_Float16)sb.z; o[7] = (_Float16)sb.w;
        *(h8*)ob = o;
#pragma unroll
        for (int ro = 1; ro < 4; ++ro) {
            float4 aa = *(const float4*)&wsum[f][ro0 + ro + 8][w];
            float4 ab = *(const float4*)&wsum[f][ro0 + ro + 8][w + 4];
            float4 ba = *(const float4*)&wsum[f][ro0 + ro - 1][w];
            float4 bb = *(const float4*)&wsum[f][ro0 + ro - 1][w + 4];
            sa.x += aa.x - ba.x; sa.y += aa.y - ba.y;
            sa.z += aa.z - ba.z; sa.w += aa.w - ba.w;
            sb.x += ab.x - bb.x; sb.y += ab.y - bb.y;
            sb.z += ab.z - bb.z; sb.w += ab.w - bb.w;
            o[0] = (_Float16)sa.x; o[1] = (_Float16)sa.y;
            o[2] = (_Float16)sa.z; o[3] = (_Float16)sa.w;
            o[4] = (_Float16)sb.x; o[5] = (_Float16)sb.y;
            o[6] = (_Float16)sb.z; o[7] = (_Float16)sb.w;
            *(h8*)(ob + (size_t)ro * WW) = o;
        }
    }
}

// ---------------------------------------------------------------------------
// Kernel 2 (v3): sliding-window D-sum on fp16 fields, 4 columns/thread,
// 8B h4 loads, float4 running sums. Grid (25, 8, NB).
// ---------------------------------------------------------------------------
__global__ __launch_bounds__(256) void ncc_dred(const _Float16* __restrict__ fields,
                                                float* __restrict__ partial) {
    const int hw = (blockIdx.x * 256 + threadIdx.x) * 4;   // 0..25596
    const int d0 = blockIdx.y * DCH;
    const _Float16* p0 = fields + (size_t)blockIdx.z * 5 * VOL + hw;

    float4 s0 = {0,0,0,0}, s1 = {0,0,0,0}, s2 = {0,0,0,0},
           s3 = {0,0,0,0}, s4 = {0,0,0,0};
    {
        int lo = d0 - 4 > 0 ? d0 - 4 : 0;
        int hi = d0 + 4 < DD - 1 ? d0 + 4 : DD - 1;
        for (int dd = lo; dd <= hi; ++dd) {
            const _Float16* p = p0 + (size_t)dd * PLANE;
            h4 v0 = *(const h4*)(p + 0 * (size_t)VOL);
            h4 v1 = *(const h4*)(p + 1 * (size_t)VOL);
            h4 v2 = *(const h4*)(p + 2 * (size_t)VOL);
            h4 v3 = *(const h4*)(p + 3 * (size_t)VOL);
            h4 v4 = *(const h4*)(p + 4 * (size_t)VOL);
            s0.x += (float)v0.x; s0.y += (float)v0.y; s0.z += (float)v0.z; s0.w += (float)v0.w;
            s1.x += (float)v1.x; s1.y += (float)v1.y; s1.z += (float)v1.z; s1.w += (float)v1.w;
            s2.x += (float)v2.x; s2.y += (float)v2.y; s2.z += (float)v2.z; s2.w += (float)v2.w;
            s3.x += (float)v3.x; s3.y += (float)v3.y; s3.z += (float)v3.z; s3.w += (float)v3.w;
            s4.x += (float)v4.x; s4.y += (float)v4.y; s4.z += (float)v4.z; s4.w += (float)v4.w;
        }
    }

    float acc = 0.f;
    const float inv_win = 1.0f / 729.0f;
#define CC_ONE(c) {                                                        \
        float cross = fmaf(-(s0.c * s1.c), inv_win, s4.c);                 \
        float pv = fmaxf(fmaf(-(s0.c * s0.c), inv_win, s2.c), 0.f);        \
        float tv = fmaxf(fmaf(-(s1.c * s1.c), inv_win, s3.c), 0.f);        \
        float cc = cross * cross / (pv * tv + 0.001f);                     \
        acc += fminf(fmaxf(cc, 0.f), 1.f); }

    for (int d = d0; d < d0 + DCH; ++d) {
        CC_ONE(x) CC_ONE(y) CC_ONE(z) CC_ONE(w)

        if (d + 1 < d0 + DCH) {
            if (d + 5 < DD) {
                const _Float16* p = p0 + (size_t)(d + 5) * PLANE;
                h4 v0 = *(const h4*)(p + 0 * (size_t)VOL);
                h4 v1 = *(const h4*)(p + 1 * (size_t)VOL);
                h4 v2 = *(const h4*)(p + 2 * (size_t)VOL);
                h4 v3 = *(const h4*)(p + 3 * (size_t)VOL);
                h4 v4 = *(const h4*)(p + 4 * (size_t)VOL);
                s0.x += (float)v0.x; s0.y += (float)v0.y; s0.z += (float)v0.z; s0.w += (float)v0.w;
                s1.x += (float)v1.x; s1.y += (float)v1.y; s1.z += (float)v1.z; s1.w += (float)v1.w;
                s2.x += (float)v2.x; s2.y += (float)v2.y; s2.z += (float)v2.z; s2.w += (float)v2.w;
                s3.x += (float)v3.x; s3.y += (float)v3.y; s3.z += (float)v3.z; s3.w += (float)v3.w;
                s4.x += (float)v4.x; s4.y += (float)v4.y; s4.z += (float)v4.z; s4.w += (float)v4.w;
            }
            if (d - 4 >= 0) {
                const _Float16* p = p0 + (size_t)(d - 4) * PLANE;
                h4 v0 = *(const h4*)(p + 0 * (size_t)VOL);
                h4 v1 = *(const h4*)(p + 1 * (size_t)VOL);
                h4 v2 = *(const h4*)(p + 2 * (size_t)VOL);
                h4 v3 = *(const h4*)(p + 3 * (size_t)VOL);
                h4 v4 = *(const h4*)(p + 4 * (size_t)VOL);
                s0.x -= (float)v0.x; s0.y -= (float)v0.y; s0.z -= (float)v0.z; s0.w -= (float)v0.w;
                s1.x -= (float)v1.x; s1.y -= (float)v1.y; s1.z -= (float)v1.z; s1.w -= (float)v1.w;
                s2.x -= (float)v2.x; s2.y -= (float)v2.y; s2.z -= (float)v2.z; s2.w -= (float)v2.w;
                s3.x -= (float)v3.x; s3.y -= (float)v3.y; s3.z -= (float)v3.z; s3.w -= (float)v3.w;
                s4.x -= (float)v4.x; s4.y -= (float)v4.y; s4.z -= (float)v4.z; s4.w -= (float)v4.w;
            }
        }
    }
#undef CC_ONE

    for (int o = 32; o > 0; o >>= 1) acc += __shfl_down(acc, o, 64);
    __shared__ float red[4];
    int lane = threadIdx.x & 63, wid = threadIdx.x >> 6;
    if (lane == 0) red[wid] = acc;
    __syncthreads();
    if (threadIdx.x == 0)
        partial[((size_t)blockIdx.z * NDCH + blockIdx.y) * CPT + blockIdx.x] =
            red[0] + red[1] + red[2] + red[3];
}

// ---------------------------------------------------------------------------
// Kernel 3: L1 gradient penalty — d-walking float4 chunks.
// ---------------------------------------------------------------------------
__global__ __launch_bounds__(256) void grad_red(const float* __restrict__ fl,
                                                float* __restrict__ partial) {
    const int gid = blockIdx.x * 256 + threadIdx.x;  // 0..307199
    const int w4  = gid % 40;
    int t = gid / 40;
    const int h  = t % HH;  t /= HH;
    const int dc = t % (DD / GCHD); t /= (DD / GCHD);
    const int bc = t;                                // 0..5
    const int d0 = dc * GCHD;
    const int w  = w4 * 4;

    const float* base = fl + (size_t)bc * VOL;
    float acc = 0.f;
    float4 v = *(const float4*)(base + ((size_t)d0 * HH + h) * WW + w);
    for (int d = d0; d < d0 + GCHD; ++d) {
        const float* pd = base + ((size_t)d * HH + h) * WW + w;
        float4 vn = v;
        if (d < DD - 1) {
            vn = *(const float4*)(pd + PLANE);
            acc += fabsf(vn.x - v.x) + fabsf(vn.y - v.y) +
                   fabsf(vn.z - v.z) + fabsf(vn.w - v.w);
        }
        if (h < HH - 1) {
            float4 vh = *(const float4*)(pd + WW);
            acc += fabsf(vh.x - v.x) + fabsf(vh.y - v.y) +
                   fabsf(vh.z - v.z) + fabsf(vh.w - v.w);
        }
        acc += fabsf(v.y - v.x) + fabsf(v.z - v.y) + fabsf(v.w - v.z);
        if (w < WW - 4) acc += fabsf(pd[4] - v.w);
        v = vn;
    }

    for (int o = 32; o > 0; o >>= 1) acc += __shfl_down(acc, o, 64);
    __shared__ float red[4];
    int lane = threadIdx.x & 63, wid = threadIdx.x >> 6;
    if (lane == 0) red[wid] = acc;
    __syncthreads();
    if (threadIdx.x == 0) partial[blockIdx.x] = red[0] + red[1] + red[2] + red[3];
}

// ---------------------------------------------------------------------------
// Kernel 4: final deterministic reduction of partials -> scalar loss
// ---------------------------------------------------------------------------
__global__ __launch_bounds__(256) void finalize(const float* __restrict__ pcc, int ncc,
                                                const float* __restrict__ pg, int ng,
                                                float* __restrict__ out) {
    __shared__ float red[4];
    int lane = threadIdx.x & 63, wid = threadIdx.x >> 6;

    float a = 0.f;
    for (int i = threadIdx.x; i < ncc; i += 256) a += pcc[i];
    for (int o = 32; o > 0; o >>= 1) a += __shfl_down(a, o, 64);
    if (lane == 0) red[wid] = a;
    __syncthreads();
    float asum = red[0] + red[1] + red[2] + red[3];
    __syncthreads();

    float g = 0.f;
    for (int i = threadIdx.x; i < ng; i += 256) g += pg[i];
    for (int o = 32; o > 0; o >>= 1) g += __shfl_down(g, o, 64);
    if (lane == 0) red[wid] = g;
    __syncthreads();
    float gsum = red[0] + red[1] + red[2] + red[3];

    if (threadIdx.x == 0) {
        float sim = 1.0f - asum / 8192000.0f;          // mean over (2,1,160,160,160)
        float reg = gsum / 73267200.0f;                // 3 * (2*3*159*160*160)
        out[0] = sim + reg;
    }
}

// ---------------------------------------------------------------------------
extern "C" void kernel_launch(void* const* d_in, const int* in_sizes, int n_in,
                              void* d_out, int out_size, void* d_ws, size_t ws_size,
                              hipStream_t stream) {
    const float* moved  = (const float*)d_in[0];
    const float* fixedp = (const float*)d_in[1];
    const float* flow   = (const float*)d_in[2];
    float* out = (float*)d_out;

    _Float16* fields = (_Float16*)d_ws;               // NB*5*VOL fp16 (81.9 MB)
    float* pcc = (float*)(fields + (size_t)NB * 5 * VOL);  // NB*DREDBLK floats
    float* pg  = pcc + NB * DREDBLK;                  // GBLK floats

    grad_red<<<GBLK, 256, 0, stream>>>(flow, pg);
    ncc_wh<<<dim3(HH / HT, DD, NB), 512, 0, stream>>>(moved, fixedp, fields);
    ncc_dred<<<dim3(CPT, NDCH, NB), 256, 0, stream>>>(fields, pcc);
    finalize<<<1, 256, 0, stream>>>(pcc, NB * DREDBLK, pg, GBLK, out);
}

// Round 7
// 97.336 us; speedup vs baseline: 1.0298x; 1.0298x over previous
//
#include <hip/hip_runtime.h>

#define DD 160
#define HH 160
#define WW 160
#define VOL (DD * HH * WW)   // per-batch volume = 4,096,000
#define PLANE (HH * WW)      // 25,600
#define NB 2
#define HT 16                // output h-rows per wh block
#define HS (HT + 8)          // staged rows = 24
#define LDWH 168             // LDS row stride in halves; 336B, 16B-aligned, 84%32=20 banks
#define DCH 10               // d-outputs per ncc_dred block
#define NDCH (DD / DCH)      // 16
#define CPT 50               // column-pair tiles: 12800 pairs / 256
#define DREDBLK (CPT * NDCH) // 800 per batch
#define GCHD 20              // grad d-chunk
#define GBLK (NB * 3 * (DD / GCHD) * HH * (WW / 4) / 256)   // 1200

typedef _Float16 h8 __attribute__((ext_vector_type(8)));
typedef _Float16 h2 __attribute__((ext_vector_type(2)));

// ---------------------------------------------------------------------------
// Kernel 1 (v6): fused W+H box sums of 5 moment fields -> fp16 fields.
// fp16 wsum in LDS (40.3 KB -> 3 blocks/CU, 24 waves/CU).
// Block: 512 thr, output 16h x 160w at one (d, b). Grid (10, 160, 2).
// ---------------------------------------------------------------------------
__global__ __launch_bounds__(512, 6) void ncc_wh(const float* __restrict__ mv,
                                                 const float* __restrict__ fx,
                                                 _Float16* __restrict__ out) {
    __shared__ _Float16 wsum[5][HS][LDWH];

    const int d   = blockIdx.y;
    const int b   = blockIdx.z;
    const int h0  = blockIdx.x * HT;
    const int tid = threadIdx.x;

    if (tid < 480) {
        const int r  = tid / 20;        // 0..23 staged row
        const int s  = tid - r * 20;    // 0..19 w-segment
        const int h  = h0 - 4 + r;
        const int w0 = 8 * s;

        float vm[16], vf[16];
#pragma unroll
        for (int i = 0; i < 16; ++i) { vm[i] = 0.f; vf[i] = 0.f; }

        if ((unsigned)h < (unsigned)HH) {
            const float* rowm = mv + (size_t)b * VOL + ((size_t)d * HH + h) * WW;
            const float* rowf = fx + (size_t)b * VOL + ((size_t)d * HH + h) * WW;
#pragma unroll
            for (int j = 0; j < 4; ++j) {
                const int w4 = w0 - 4 + 4 * j;
                if (w4 >= 0 && w4 <= WW - 4) {
                    float4 m4 = *(const float4*)(rowm + w4);
                    float4 f4 = *(const float4*)(rowf + w4);
                    vm[4*j+0] = m4.x; vm[4*j+1] = m4.y; vm[4*j+2] = m4.z; vm[4*j+3] = m4.w;
                    vf[4*j+0] = f4.x; vf[4*j+1] = f4.y; vf[4*j+2] = f4.z; vf[4*j+3] = f4.w;
                } else {
#pragma unroll
                    for (int e = 0; e < 4; ++e) {
                        const int w = w4 + e;
                        if ((unsigned)w < (unsigned)WW) {
                            vm[4*j+e] = rowm[w];
                            vf[4*j+e] = rowf[w];
                        }
                    }
                }
            }
        }

        float o0[8], o1[8], o2[8], o3[8], o4[8];
        float sm = 0.f, sf = 0.f, smm = 0.f, sff = 0.f, smf = 0.f;
#pragma unroll
        for (int i = 0; i < 9; ++i) {
            float m = vm[i], f = vf[i];
            sm += m; sf += f;
            smm = fmaf(m, m, smm);
            sff = fmaf(f, f, sff);
            smf = fmaf(m, f, smf);
        }
        o0[0] = sm; o1[0] = sf; o2[0] = smm; o3[0] = sff; o4[0] = smf;
#pragma unroll
        for (int k = 1; k < 8; ++k) {
            float am = vm[k + 8], bm = vm[k - 1];
            float af = vf[k + 8], bf = vf[k - 1];
            sm  += am - bm;
            sf  += af - bf;
            smm += fmaf(am, am, -(bm * bm));
            sff += fmaf(af, af, -(bf * bf));
            smf += fmaf(am, af, -(bm * bf));
            o0[k] = sm; o1[k] = sf; o2[k] = smm; o3[k] = sff; o4[k] = smf;
        }
#define PACK_STORE(fi, arr) {                                   \
            h8 t_;                                              \
            _Pragma("unroll")                                   \
            for (int j_ = 0; j_ < 8; ++j_) t_[j_] = (_Float16)arr[j_]; \
            *(h8*)&wsum[fi][r][w0] = t_; }
        PACK_STORE(0, o0) PACK_STORE(1, o1) PACK_STORE(2, o2)
        PACK_STORE(3, o3) PACK_STORE(4, o4)
#undef PACK_STORE
    }
    __syncthreads();

    if (tid < 400) {
        const int f   = tid / 80;                 // field 0..4
        const int rem = tid - f * 80;
        const int q   = rem / 20;                 // row-quarter 0..3
        const int w   = 8 * (rem - q * 20);       // 0..152
        const int ro0 = 4 * q;

        float sa[8];
#pragma unroll
        for (int j = 0; j < 8; ++j) sa[j] = 0.f;
#pragma unroll
        for (int t = 0; t < 9; ++t) {
            h8 v = *(const h8*)&wsum[f][ro0 + t][w];
#pragma unroll
            for (int j = 0; j < 8; ++j) sa[j] += (float)v[j];
        }
        _Float16* ob = out + (size_t)(b * 5 + f) * VOL
                           + ((size_t)d * HH + h0 + ro0) * WW + w;
        h8 o;
#pragma unroll
        for (int j = 0; j < 8; ++j) o[j] = (_Float16)sa[j];
        *(h8*)ob = o;
#pragma unroll
        for (int ro = 1; ro < 4; ++ro) {
            h8 va = *(const h8*)&wsum[f][ro0 + ro + 8][w];
            h8 vb = *(const h8*)&wsum[f][ro0 + ro - 1][w];
#pragma unroll
            for (int j = 0; j < 8; ++j) sa[j] += (float)va[j] - (float)vb[j];
#pragma unroll
            for (int j = 0; j < 8; ++j) o[j] = (_Float16)sa[j];
            *(h8*)(ob + (size_t)ro * WW) = o;
        }
    }
}

// ---------------------------------------------------------------------------
// Kernel 2 (v4): sliding-window D-sum on fp16 fields, 2 columns/thread,
// DCH=10 -> grid (50,16,2) = 1600 blocks (6.25 waves/SIMD for latency hiding).
// ---------------------------------------------------------------------------
__global__ __launch_bounds__(256) void ncc_dred(const _Float16* __restrict__ fields,
                                                float* __restrict__ partial) {
    const int hw = (blockIdx.x * 256 + threadIdx.x) * 2;   // 0..25598 even
    const int d0 = blockIdx.y * DCH;
    const _Float16* p0 = fields + (size_t)blockIdx.z * 5 * VOL + hw;

    float s0a = 0.f, s1a = 0.f, s2a = 0.f, s3a = 0.f, s4a = 0.f;
    float s0b = 0.f, s1b = 0.f, s2b = 0.f, s3b = 0.f, s4b = 0.f;
    {
        int lo = d0 - 4 > 0 ? d0 - 4 : 0;
        int hi = d0 + 4 < DD - 1 ? d0 + 4 : DD - 1;
        for (int dd = lo; dd <= hi; ++dd) {
            const _Float16* p = p0 + (size_t)dd * PLANE;
            h2 v0 = *(const h2*)(p + 0 * (size_t)VOL);
            h2 v1 = *(const h2*)(p + 1 * (size_t)VOL);
            h2 v2 = *(const h2*)(p + 2 * (size_t)VOL);
            h2 v3 = *(const h2*)(p + 3 * (size_t)VOL);
            h2 v4 = *(const h2*)(p + 4 * (size_t)VOL);
            s0a += (float)v0.x; s0b += (float)v0.y;
            s1a += (float)v1.x; s1b += (float)v1.y;
            s2a += (float)v2.x; s2b += (float)v2.y;
            s3a += (float)v3.x; s3b += (float)v3.y;
            s4a += (float)v4.x; s4b += (float)v4.y;
        }
    }

    float acc = 0.f;
    const float inv_win = 1.0f / 729.0f;
    for (int d = d0; d < d0 + DCH; ++d) {
        {   // col a
            float cross = fmaf(-(s0a * s1a), inv_win, s4a);
            float pv = fmaxf(fmaf(-(s0a * s0a), inv_win, s2a), 0.f);
            float tv = fmaxf(fmaf(-(s1a * s1a), inv_win, s3a), 0.f);
            float cc = cross * cross / (pv * tv + 0.001f);
            acc += fminf(fmaxf(cc, 0.f), 1.f);
        }
        {   // col b
            float cross = fmaf(-(s0b * s1b), inv_win, s4b);
            float pv = fmaxf(fmaf(-(s0b * s0b), inv_win, s2b), 0.f);
            float tv = fmaxf(fmaf(-(s1b * s1b), inv_win, s3b), 0.f);
            float cc = cross * cross / (pv * tv + 0.001f);
            acc += fminf(fmaxf(cc, 0.f), 1.f);
        }

        if (d + 1 < d0 + DCH) {
            if (d + 5 < DD) {
                const _Float16* p = p0 + (size_t)(d + 5) * PLANE;
                h2 v0 = *(const h2*)(p + 0 * (size_t)VOL);
                h2 v1 = *(const h2*)(p + 1 * (size_t)VOL);
                h2 v2 = *(const h2*)(p + 2 * (size_t)VOL);
                h2 v3 = *(const h2*)(p + 3 * (size_t)VOL);
                h2 v4 = *(const h2*)(p + 4 * (size_t)VOL);
                s0a += (float)v0.x; s0b += (float)v0.y;
                s1a += (float)v1.x; s1b += (float)v1.y;
                s2a += (float)v2.x; s2b += (float)v2.y;
                s3a += (float)v3.x; s3b += (float)v3.y;
                s4a += (float)v4.x; s4b += (float)v4.y;
            }
            if (d - 4 >= 0) {
                const _Float16* p = p0 + (size_t)(d - 4) * PLANE;
                h2 v0 = *(const h2*)(p + 0 * (size_t)VOL);
                h2 v1 = *(const h2*)(p + 1 * (size_t)VOL);
                h2 v2 = *(const h2*)(p + 2 * (size_t)VOL);
                h2 v3 = *(const h2*)(p + 3 * (size_t)VOL);
                h2 v4 = *(const h2*)(p + 4 * (size_t)VOL);
                s0a -= (float)v0.x; s0b -= (float)v0.y;
                s1a -= (float)v1.x; s1b -= (float)v1.y;
                s2a -= (float)v2.x; s2b -= (float)v2.y;
                s3a -= (float)v3.x; s3b -= (float)v3.y;
                s4a -= (float)v4.x; s4b -= (float)v4.y;
            }
        }
    }

    for (int o = 32; o > 0; o >>= 1) acc += __shfl_down(acc, o, 64);
    __shared__ float red[4];
    int lane = threadIdx.x & 63, wid = threadIdx.x >> 6;
    if (lane == 0) red[wid] = acc;
    __syncthreads();
    if (threadIdx.x == 0)
        partial[((size_t)blockIdx.z * NDCH + blockIdx.y) * CPT + blockIdx.x] =
            red[0] + red[1] + red[2] + red[3];
}

// ---------------------------------------------------------------------------
// Kernel 3: L1 gradient penalty — d-walking float4 chunks.
// ---------------------------------------------------------------------------
__global__ __launch_bounds__(256) void grad_red(const float* __restrict__ fl,
                                                float* __restrict__ partial) {
    const int gid = blockIdx.x * 256 + threadIdx.x;  // 0..307199
    const int w4  = gid % 40;
    int t = gid / 40;
    const int h  = t % HH;  t /= HH;
    const int dc = t % (DD / GCHD); t /= (DD / GCHD);
    const int bc = t;                                // 0..5
    const int d0 = dc * GCHD;
    const int w  = w4 * 4;

    const float* base = fl + (size_t)bc * VOL;
    float acc = 0.f;
    float4 v = *(const float4*)(base + ((size_t)d0 * HH + h) * WW + w);
    for (int d = d0; d < d0 + GCHD; ++d) {
        const float* pd = base + ((size_t)d * HH + h) * WW + w;
        float4 vn = v;
        if (d < DD - 1) {
            vn = *(const float4*)(pd + PLANE);
            acc += fabsf(vn.x - v.x) + fabsf(vn.y - v.y) +
                   fabsf(vn.z - v.z) + fabsf(vn.w - v.w);
        }
        if (h < HH - 1) {
            float4 vh = *(const float4*)(pd + WW);
            acc += fabsf(vh.x - v.x) + fabsf(vh.y - v.y) +
                   fabsf(vh.z - v.z) + fabsf(vh.w - v.w);
        }
        acc += fabsf(v.y - v.x) + fabsf(v.z - v.y) + fabsf(v.w - v.z);
        if (w < WW - 4) acc += fabsf(pd[4] - v.w);
        v = vn;
    }

    for (int o = 32; o > 0; o >>= 1) acc += __shfl_down(acc, o, 64);
    __shared__ float red[4];
    int lane = threadIdx.x & 63, wid = threadIdx.x >> 6;
    if (lane == 0) red[wid] = acc;
    __syncthreads();
    if (threadIdx.x == 0) partial[blockIdx.x] = red[0] + red[1] + red[2] + red[3];
}

// ---------------------------------------------------------------------------
// Kernel 4: final deterministic reduction of partials -> scalar loss
// ---------------------------------------------------------------------------
__global__ __launch_bounds__(256) void finalize(const float* __restrict__ pcc, int ncc,
                                                const float* __restrict__ pg, int ng,
                                                float* __restrict__ out) {
    __shared__ float red[4];
    int lane = threadIdx.x & 63, wid = threadIdx.x >> 6;

    float a = 0.f;
    for (int i = threadIdx.x; i < ncc; i += 256) a += pcc[i];
    for (int o = 32; o > 0; o >>= 1) a += __shfl_down(a, o, 64);
    if (lane == 0) red[wid] = a;
    __syncthreads();
    float asum = red[0] + red[1] + red[2] + red[3];
    __syncthreads();

    float g = 0.f;
    for (int i = threadIdx.x; i < ng; i += 256) g += pg[i];
    for (int o = 32; o > 0; o >>= 1) g += __shfl_down(g, o, 64);
    if (lane == 0) red[wid] = g;
    __syncthreads();
    float gsum = red[0] + red[1] + red[2] + red[3];

    if (threadIdx.x == 0) {
        float sim = 1.0f - asum / 8192000.0f;          // mean over (2,1,160,160,160)
        float reg = gsum / 73267200.0f;                // 3 * (2*3*159*160*160)
        out[0] = sim + reg;
    }
}

// ---------------------------------------------------------------------------
extern "C" void kernel_launch(void* const* d_in, const int* in_sizes, int n_in,
                              void* d_out, int out_size, void* d_ws, size_t ws_size,
                              hipStream_t stream) {
    const float* moved  = (const float*)d_in[0];
    const float* fixedp = (const float*)d_in[1];
    const float* flow   = (const float*)d_in[2];
    float* out = (float*)d_out;

    _Float16* fields = (_Float16*)d_ws;               // NB*5*VOL fp16 (81.9 MB)
    float* pcc = (float*)(fields + (size_t)NB * 5 * VOL);  // NB*DREDBLK floats
    float* pg  = pcc + NB * DREDBLK;                  // GBLK floats

    grad_red<<<GBLK, 256, 0, stream>>>(flow, pg);
    ncc_wh<<<dim3(HH / HT, DD, NB), 512, 0, stream>>>(moved, fixedp, fields);
    ncc_dred<<<dim3(CPT, NDCH, NB), 256, 0, stream>>>(fields, pcc);
    finalize<<<1, 256, 0, stream>>>(pcc, NB * DREDBLK, pg, GBLK, out);
}